// Round 1
// baseline (3553.763 us; speedup 1.0000x reference)
//
#include <hip/hip_runtime.h>
#include <hip/hip_bf16.h>
#include <math.h>

// Problem dims (fixed by the reference)
#define NB 64      // batch
#define NS 64      // encoder steps
#define NL 64      // decoder steps
#define NH 256     // hidden
#define G3 768     // 3*NH (gates r,z,n)
#define NVIN 10000
#define NVOUT 10000

// ---------------------------------------------------------------------------
// Transpose [rows x cols] (row stride in_stride) -> out [cols x rows]
// Used to get K-major recurrent weights for coalesced reads in the scan.
// ---------------------------------------------------------------------------
__global__ __launch_bounds__(256) void k_transpose(
    const float* __restrict__ in, float* __restrict__ out,
    int rows, int cols, int in_stride) {
  int idx = blockIdx.x * 256 + threadIdx.x;
  if (idx < rows * cols) {
    int r = idx % rows;          // consecutive idx -> consecutive out addr
    int c = idx / rows;
    out[idx] = in[r * in_stride + c];   // out[c][r] = in[r][c]
  }
}

// ---------------------------------------------------------------------------
// GEMM1: Gienc[m][n] = X_row(m) . enc_Wih[n] + bih[n]
//   m = s*64+b (4096), n = 0..767, K = 10000. NT layout (both K-contiguous).
// 64x64 tile, 256 threads, 4x4 microtile, K-tile 40, LDS stored transposed
// (As[k][row]) so the inner loop does float4 LDS reads.
// ---------------------------------------------------------------------------
#define KT1 40
__global__ __launch_bounds__(256) void k_gemm_enc(
    const float* __restrict__ X, const float* __restrict__ W,
    const float* __restrict__ bias, float* __restrict__ out) {
  __shared__ float As[KT1][72];   // pad 72: 16B-aligned float4 rows, spread banks
  __shared__ float Bs[KT1][72];
  int t = threadIdx.x;
  int m0 = blockIdx.y * 64, n0 = blockIdx.x * 64;
  int tr = t >> 4, tc = t & 15;
  float acc[4][4] = {};
  for (int k0 = 0; k0 < NVIN; k0 += KT1) {
    __syncthreads();
#pragma unroll
    for (int i = 0; i < 10; ++i) {            // 2560 elems / 256 thr
      int idx = i * 256 + t;
      int r = idx / KT1, c = idx % KT1;
      int m = m0 + r;                          // m = s*64+b ; X row is (b,s)
      As[c][r] = X[(((m & 63) << 6) + (m >> 6)) * NVIN + k0 + c];
      Bs[c][r] = W[(n0 + r) * NVIN + k0 + c];
    }
    __syncthreads();
#pragma unroll 8
    for (int kk = 0; kk < KT1; ++kk) {
      float4 a = *(const float4*)(&As[kk][tr * 4]);
      float4 b = *(const float4*)(&Bs[kk][tc * 4]);
      acc[0][0] += a.x * b.x; acc[0][1] += a.x * b.y; acc[0][2] += a.x * b.z; acc[0][3] += a.x * b.w;
      acc[1][0] += a.y * b.x; acc[1][1] += a.y * b.y; acc[1][2] += a.y * b.z; acc[1][3] += a.y * b.w;
      acc[2][0] += a.z * b.x; acc[2][1] += a.z * b.y; acc[2][2] += a.z * b.z; acc[2][3] += a.z * b.w;
      acc[3][0] += a.w * b.x; acc[3][1] += a.w * b.y; acc[3][2] += a.w * b.z; acc[3][3] += a.w * b.w;
    }
  }
#pragma unroll
  for (int i = 0; i < 4; ++i)
#pragma unroll
    for (int j = 0; j < 4; ++j) {
      int n = n0 + tc * 4 + j;
      out[(m0 + tr * 4 + i) * G3 + n] = acc[i][j] + bias[n];
    }
}

// ---------------------------------------------------------------------------
// Pre-gather decoder one-hot input term (teacher forcing is known upfront):
// Gdec[(i*64+b)][g] = dec_bih[g] + (i>0 ? dec_Wih[g][NH + gt[b][i-1]] : 0)
// ---------------------------------------------------------------------------
__global__ __launch_bounds__(256) void k_pregather(
    const float* __restrict__ Wih, const float* __restrict__ bih,
    const int* __restrict__ gt, float* __restrict__ Gdec) {
  int ib = blockIdx.x;              // i*64+b
  int i = ib >> 6, b = ib & 63;
  int tok = (i > 0) ? gt[b * NL + (i - 1)] : -1;
  for (int g = threadIdx.x; g < G3; g += 256) {
    float v = bih[g];
    if (tok >= 0) v += Wih[g * (NH + NVOUT) + NH + tok];
    Gdec[ib * G3 + g] = v;
  }
}

// ---------------------------------------------------------------------------
// Encoder scan: 32 WGs x 768 thr, 2 batches per WG (independent recurrences).
// Per step: gh = h @ WhhT (thread g does one column for both batches),
// then gates/h-update on threads < 512.
// ---------------------------------------------------------------------------
__global__ __launch_bounds__(768) void k_encoder(
    const float* __restrict__ Gi, const float* __restrict__ WhhT,
    const float* __restrict__ bhh, float* __restrict__ enc_h) {
  __shared__ float hbuf[2][NH];
  __shared__ float ghbuf[2][G3];
  int t = threadIdx.x;
  int b0 = blockIdx.x * 2;
  if (t < 512) hbuf[t >> 8][t & 255] = 0.f;
  __syncthreads();
  for (int s = 0; s < NS; ++s) {
    {   // all 768 threads: one gate-column each, both batches share the load
      int g = t;
      float a0 = 0.f, a1 = 0.f;
#pragma unroll 8
      for (int k = 0; k < NH; ++k) {
        float w = WhhT[k * G3 + g];
        a0 = fmaf(hbuf[0][k], w, a0);
        a1 = fmaf(hbuf[1][k], w, a1);
      }
      float bb = bhh[g];
      ghbuf[0][g] = a0 + bb;
      ghbuf[1][g] = a1 + bb;
    }
    __syncthreads();
    if (t < 512) {
      int bl = t >> 8, j = t & 255, b = b0 + bl;
      const float* gi = Gi + (s * 64 + b) * G3;
      float r = 1.f / (1.f + __expf(-(gi[j] + ghbuf[bl][j])));
      float z = 1.f / (1.f + __expf(-(gi[256 + j] + ghbuf[bl][256 + j])));
      float n = tanhf(gi[512 + j] + r * ghbuf[bl][512 + j]);
      float hn = (1.f - z) * n + z * hbuf[bl][j];
      hbuf[bl][j] = hn;
      enc_h[(s * 64 + b) * NH + j] = hn;
    }
    __syncthreads();
  }
}

// enc_score[s][b] = enc_h[s][b] . w_enc   (w_enc = att_w[256:512])
__global__ __launch_bounds__(256) void k_enc_score(
    const float* __restrict__ enc_h, const float* __restrict__ att_w,
    float* __restrict__ score) {
  int row = blockIdx.x * 4 + (threadIdx.x >> 6);
  int lane = threadIdx.x & 63;
  const float* hrow = enc_h + row * NH;
  const float* we = att_w + NH;
  float p = 0.f;
#pragma unroll
  for (int j = lane; j < NH; j += 64) p += hrow[j] * we[j];
#pragma unroll
  for (int off = 32; off; off >>= 1) p += __shfl_xor(p, off, 64);
  if (lane == 0) score[row] = p;
}

// ---------------------------------------------------------------------------
// Decoder scan: 32 WGs x 768 thr, 2 batches per WG.
// Per step: attention score -> softmax over S -> ctx -> gi/gh dots -> gates.
// ---------------------------------------------------------------------------
__global__ __launch_bounds__(768) void k_decoder(
    const float* __restrict__ Gdec, const float* __restrict__ WihT,
    const float* __restrict__ WhhT, const float* __restrict__ bhh,
    const float* __restrict__ enc_h, const float* __restrict__ escore,
    const float* __restrict__ att_w, const float* __restrict__ att_b,
    float* __restrict__ dec_h) {
  __shared__ float hbuf[2][NH];
  __shared__ float ctx[2][NH];
  __shared__ float gibuf[2][G3];
  __shared__ float ghbuf[2][G3];
  __shared__ float wts[2][NS];
  __shared__ float sc[2];
  int t = threadIdx.x;
  int b0 = blockIdx.x * 2;
  // h0 = encoder h at s = S-1
  if (t < 512) {
    int bl = t >> 8, j = t & 255;
    hbuf[bl][j] = enc_h[((NS - 1) * 64 + b0 + bl) * NH + j];
  }
  __syncthreads();
  float attb = att_b[0];
  for (int i = 0; i < NL; ++i) {
    // A: score_b = h . w_dec (waves 0/1, one per batch)
    if (t < 128) {
      int bl = t >> 6, lane = t & 63;
      float p = 0.f;
#pragma unroll
      for (int j = lane; j < NH; j += 64) p += hbuf[bl][j] * att_w[j];
#pragma unroll
      for (int off = 32; off; off >>= 1) p += __shfl_xor(p, off, 64);
      if (lane == 0) sc[bl] = p;
    }
    __syncthreads();
    // B: softmax over S of relu(enc_score + score_b + att_b)
    if (t < 128) {
      int bl = t >> 6, s_ = t & 63, b = b0 + bl;
      float lg = fmaxf(escore[s_ * 64 + b] + sc[bl] + attb, 0.f);
      float mx = lg;
#pragma unroll
      for (int off = 32; off; off >>= 1) mx = fmaxf(mx, __shfl_xor(mx, off, 64));
      float e = __expf(lg - mx);
      float sm = e;
#pragma unroll
      for (int off = 32; off; off >>= 1) sm += __shfl_xor(sm, off, 64);
      wts[bl][s_] = e / sm;
    }
    __syncthreads();
    // C: ctx = sum_s wts[s] * enc_h[s,b,:]
    if (t < 512) {
      int bl = t >> 8, j = t & 255, b = b0 + bl;
      float c = 0.f;
#pragma unroll 4
      for (int s_ = 0; s_ < NS; ++s_) c += wts[bl][s_] * enc_h[(s_ * 64 + b) * NH + j];
      ctx[bl][j] = c;
    }
    __syncthreads();
    // D: gi = ctx @ WihT (+pre-gathered one-hot term), gh = h @ WhhT
    {
      int g = t;
      float gi0 = 0.f, gi1 = 0.f, gh0 = 0.f, gh1 = 0.f;
#pragma unroll 4
      for (int k = 0; k < NH; ++k) {
        float wi = WihT[k * G3 + g];
        float wh = WhhT[k * G3 + g];
        gi0 = fmaf(ctx[0][k], wi, gi0);
        gi1 = fmaf(ctx[1][k], wi, gi1);
        gh0 = fmaf(hbuf[0][k], wh, gh0);
        gh1 = fmaf(hbuf[1][k], wh, gh1);
      }
      float bb = bhh[g];
      gibuf[0][g] = gi0 + Gdec[(i * 64 + b0) * G3 + g];
      gibuf[1][g] = gi1 + Gdec[(i * 64 + b0 + 1) * G3 + g];
      ghbuf[0][g] = gh0 + bb;
      ghbuf[1][g] = gh1 + bb;
    }
    __syncthreads();
    // E: gates + h update
    if (t < 512) {
      int bl = t >> 8, j = t & 255, b = b0 + bl;
      float r = 1.f / (1.f + __expf(-(gibuf[bl][j] + ghbuf[bl][j])));
      float z = 1.f / (1.f + __expf(-(gibuf[bl][256 + j] + ghbuf[bl][256 + j])));
      float n = tanhf(gibuf[bl][512 + j] + r * ghbuf[bl][512 + j]);
      float hn = (1.f - z) * n + z * hbuf[bl][j];
      hbuf[bl][j] = hn;
      dec_h[(i * 64 + b) * NH + j] = hn;
    }
    __syncthreads();
  }
}

// ---------------------------------------------------------------------------
// Output GEMM: out[(b*L+l)][n] = dec_h[(l*64+b)] . out_W[n] + out_b[n]
// M=4096, N=10000, K=256. Writes raw logits into d_out (log-softmaxed after).
// ---------------------------------------------------------------------------
#define KT5 32
__global__ __launch_bounds__(256) void k_gemm_out(
    const float* __restrict__ Hd, const float* __restrict__ W,
    const float* __restrict__ bias, float* __restrict__ out) {
  __shared__ float As[KT5][72];
  __shared__ float Bs[KT5][72];
  int t = threadIdx.x;
  int m0 = blockIdx.y * 64, n0 = blockIdx.x * 64;
  int tr = t >> 4, tc = t & 15;
  float acc[4][4] = {};
  for (int k0 = 0; k0 < NH; k0 += KT5) {
    __syncthreads();
#pragma unroll
    for (int i = 0; i < 8; ++i) {             // 2048 elems / 256 thr
      int idx = i * 256 + t;
      int r = idx / KT5, c = idx % KT5;
      As[c][r] = Hd[(m0 + r) * NH + k0 + c];
      int n = n0 + r;
      Bs[c][r] = (n < NVOUT) ? W[n * NH + k0 + c] : 0.f;
    }
    __syncthreads();
#pragma unroll 8
    for (int kk = 0; kk < KT5; ++kk) {
      float4 a = *(const float4*)(&As[kk][tr * 4]);
      float4 b = *(const float4*)(&Bs[kk][tc * 4]);
      acc[0][0] += a.x * b.x; acc[0][1] += a.x * b.y; acc[0][2] += a.x * b.z; acc[0][3] += a.x * b.w;
      acc[1][0] += a.y * b.x; acc[1][1] += a.y * b.y; acc[1][2] += a.y * b.z; acc[1][3] += a.y * b.w;
      acc[2][0] += a.z * b.x; acc[2][1] += a.z * b.y; acc[2][2] += a.z * b.z; acc[2][3] += a.z * b.w;
      acc[3][0] += a.w * b.x; acc[3][1] += a.w * b.y; acc[3][2] += a.w * b.z; acc[3][3] += a.w * b.w;
    }
  }
#pragma unroll
  for (int i = 0; i < 4; ++i) {
    int m = m0 + tr * 4 + i;
    int l = m >> 6, b = m & 63;
    float* orow = out + (b * NL + l) * NVOUT;
#pragma unroll
    for (int j = 0; j < 4; ++j) {
      int n = n0 + tc * 4 + j;
      if (n < NVOUT) orow[n] = acc[i][j] + bias[n];
    }
  }
}

// In-place row log-softmax over VOUT (one WG per (b,l) row).
__global__ __launch_bounds__(256) void k_logsoftmax(float* __restrict__ out) {
  float* x = out + (size_t)blockIdx.x * NVOUT;
  __shared__ float red[256];
  int t = threadIdx.x;
  float mx = -1e30f;
  for (int v = t; v < NVOUT; v += 256) mx = fmaxf(mx, x[v]);
  red[t] = mx; __syncthreads();
  for (int off = 128; off; off >>= 1) {
    if (t < off) red[t] = fmaxf(red[t], red[t + off]);
    __syncthreads();
  }
  mx = red[0]; __syncthreads();
  float sm = 0.f;
  for (int v = t; v < NVOUT; v += 256) sm += __expf(x[v] - mx);
  red[t] = sm; __syncthreads();
  for (int off = 128; off; off >>= 1) {
    if (t < off) red[t] += red[t + off];
    __syncthreads();
  }
  float lse = mx + logf(red[0]);
  for (int v = t; v < NVOUT; v += 256) x[v] -= lse;
}

// ---------------------------------------------------------------------------
extern "C" void kernel_launch(void* const* d_in, const int* in_sizes, int n_in,
                              void* d_out, int out_size, void* d_ws, size_t ws_size,
                              hipStream_t stream) {
  const float* X        = (const float*)d_in[0];
  const int*   gt       = (const int*)  d_in[1];
  const float* enc_Wih  = (const float*)d_in[2];
  const float* enc_Whh  = (const float*)d_in[3];
  const float* enc_bih  = (const float*)d_in[4];
  const float* enc_bhh  = (const float*)d_in[5];
  const float* att_w    = (const float*)d_in[6];
  const float* att_b    = (const float*)d_in[7];
  const float* dec_Wih  = (const float*)d_in[8];
  const float* dec_Whh  = (const float*)d_in[9];
  const float* dec_bih  = (const float*)d_in[10];
  const float* dec_bhh  = (const float*)d_in[11];
  const float* out_W    = (const float*)d_in[12];
  const float* out_b    = (const float*)d_in[13];
  float* out = (float*)d_out;

  // workspace carve-up (floats): total ~35.9 MB
  float* p = (float*)d_ws;
  float* WhhTe = p; p += NH * G3;          // 196608
  float* WhhTd = p; p += NH * G3;
  float* WihTd = p; p += NH * G3;          // transpose of dec_Wih[:, :NH]
  float* Gienc = p; p += NS * NB * G3;     // 3145728
  float* Gdec  = p; p += NL * NB * G3;
  float* ench  = p; p += NS * NB * NH;     // 1048576
  float* dech  = p; p += NL * NB * NH;
  float* escore = p; p += NS * NB;

  k_transpose<<<768, 256, 0, stream>>>(enc_Whh, WhhTe, G3, NH, NH);
  k_transpose<<<768, 256, 0, stream>>>(dec_Whh, WhhTd, G3, NH, NH);
  k_transpose<<<768, 256, 0, stream>>>(dec_Wih, WihTd, G3, NH, NH + NVOUT);
  k_gemm_enc<<<dim3(12, 64), 256, 0, stream>>>(X, enc_Wih, enc_bih, Gienc);
  k_pregather<<<NL * NB, 256, 0, stream>>>(dec_Wih, dec_bih, gt, Gdec);
  k_encoder<<<32, 768, 0, stream>>>(Gienc, WhhTe, enc_bhh, ench);
  k_enc_score<<<1024, 256, 0, stream>>>(ench, att_w, escore);
  k_decoder<<<32, 768, 0, stream>>>(Gdec, WihTd, WhhTd, dec_bhh, ench, escore,
                                    att_w, att_b, dech);
  k_gemm_out<<<dim3(157, 64), 256, 0, stream>>>(dech, out_W, out_b, out);
  k_logsoftmax<<<NB * NL, 256, 0, stream>>>(out);
}

// Round 2
// 2284.016 us; speedup vs baseline: 1.5559x; 1.5559x over previous
//
#include <hip/hip_runtime.h>
#include <hip/hip_bf16.h>
#include <math.h>

// Problem dims (fixed by the reference)
#define NB 64      // batch
#define NS 64      // encoder steps
#define NL 64      // decoder steps
#define NH 256     // hidden
#define G3 768     // 3*NH (gates r,z,n)
#define NVIN 10000
#define NVOUT 10000
#define KP1 10016   // NVIN padded to multiple of 32 (BK) for enc GEMM
#define NOUTP 10112 // NVOUT padded to multiple of 128 (BN) for out GEMM

typedef __attribute__((ext_vector_type(8))) short bf16x8;  // 8 bf16 (4 VGPRs)
typedef __attribute__((ext_vector_type(4))) float f32x4;   // MFMA accumulator

// async global->LDS, 16B per lane (dest must be wave-uniform base + lane*16)
__device__ __forceinline__ void gld_lds16(const __hip_bfloat16* g, __hip_bfloat16* l) {
  __builtin_amdgcn_global_load_lds(
      (const __attribute__((address_space(1))) unsigned int*)(const void*)g,
      (__attribute__((address_space(3))) unsigned int*)(void*)l, 16, 0, 0);
}

// ---------------------------------------------------------------------------
// fp32 -> bf16 row-wise convert with row/col zero-padding.
// out[r][c] = (r<in_rows && c<in_cols) ? bf16(in[r][c]) : 0
// in_cols, out_cols multiples of 4. One block per out row.
// ---------------------------------------------------------------------------
__global__ __launch_bounds__(256) void k_cvt_pad(
    const float* __restrict__ in, __hip_bfloat16* __restrict__ out,
    int in_rows, int in_cols, int out_cols) {
  int r = blockIdx.x;
  const float* src = in + (size_t)r * in_cols;
  __hip_bfloat16* dst = out + (size_t)r * out_cols;
  bool live = r < in_rows;
  for (int c = threadIdx.x * 4; c < out_cols; c += 1024) {
    __hip_bfloat16 v[4];
    if (live && c < in_cols) {
      float4 f = *(const float4*)(src + c);
      v[0] = __float2bfloat16(f.x); v[1] = __float2bfloat16(f.y);
      v[2] = __float2bfloat16(f.z); v[3] = __float2bfloat16(f.w);
    } else {
      v[0] = v[1] = v[2] = v[3] = __float2bfloat16(0.f);
    }
    *(ushort4*)(dst + c) = *(const ushort4*)v;
  }
}

// ---------------------------------------------------------------------------
// Transpose [rows x cols] (row stride in_stride) -> out [cols x rows]
// ---------------------------------------------------------------------------
__global__ __launch_bounds__(256) void k_transpose(
    const float* __restrict__ in, float* __restrict__ out,
    int rows, int cols, int in_stride) {
  int idx = blockIdx.x * 256 + threadIdx.x;
  if (idx < rows * cols) {
    int r = idx % rows;
    int c = idx / rows;
    out[idx] = in[r * in_stride + c];
  }
}

// ---------------------------------------------------------------------------
// MFMA GEMM (NT): C[m][n] = sum_k A[m][k]*B[n][k] + bias[n]
// A [4096][KP1] bf16 (row = b*64+s, X order), B [768][KP1] bf16.
// 128x128 tile, 4 waves (2x2), each wave 64x64 = 4x4 frags of 16x16x32.
// ---------------------------------------------------------------------------
__global__ __launch_bounds__(256) void k_gemm_enc_mfma(
    const __hip_bfloat16* __restrict__ A, const __hip_bfloat16* __restrict__ B,
    const float* __restrict__ bias, float* __restrict__ C) {
  __shared__ __hip_bfloat16 As[128][32];
  __shared__ __hip_bfloat16 Bs[128][32];
  int t = threadIdx.x;
  int wid = t >> 6, lane = t & 63;
  int m0 = blockIdx.y * 128, n0 = blockIdx.x * 128;
  int wr = wid >> 1, wc = wid & 1;
  f32x4 acc[4][4] = {};
  for (int k0 = 0; k0 < KP1; k0 += 32) {
    __syncthreads();                      // LDS consumed before overwrite
#pragma unroll
    for (int is = 0; is < 2; ++is) {      // 2 issues x 256 thr x 16B = 8KB tile
      int off = is * 4096 + wid * 1024 + lane * 16;  // linear byte off in tile
      int r = off >> 6, cb = (off & 63) >> 1;        // row, col(elem)
      gld_lds16(A + (size_t)(m0 + r) * KP1 + k0 + cb, &As[r][cb]);
      gld_lds16(B + (size_t)(n0 + r) * KP1 + k0 + cb, &Bs[r][cb]);
    }
    __syncthreads();                      // drains vmcnt -> staged data visible
    int r16 = lane & 15, kb = (lane >> 4) * 8;
    bf16x8 af[4], bfr[4];
#pragma unroll
    for (int i = 0; i < 4; ++i) {
      af[i]  = *(const bf16x8*)&As[wr * 64 + i * 16 + r16][kb];
      bfr[i] = *(const bf16x8*)&Bs[wc * 64 + i * 16 + r16][kb];
    }
#pragma unroll
    for (int i = 0; i < 4; ++i)
#pragma unroll
      for (int j = 0; j < 4; ++j)
        acc[i][j] = __builtin_amdgcn_mfma_f32_16x16x32_bf16(af[i], bfr[j], acc[i][j], 0, 0, 0);
  }
  int r16 = lane & 15, rg = lane >> 4;
#pragma unroll
  for (int i = 0; i < 4; ++i)
#pragma unroll
    for (int j = 0; j < 4; ++j) {
      int ccol = n0 + wc * 64 + j * 16 + r16;
      float bs = bias[ccol];
#pragma unroll
      for (int q = 0; q < 4; ++q) {
        int crow = m0 + wr * 64 + i * 16 + rg * 4 + q;
        C[(size_t)crow * G3 + ccol] = acc[i][j][q] + bs;
      }
    }
}

// ---------------------------------------------------------------------------
// MFMA GEMM out: A dec_h bf16 [4096][256] (row = l*64+b), B out_W bf16
// [10112][256] (zero-padded rows). C row (b*NL+l), col guard < NVOUT.
// ---------------------------------------------------------------------------
__global__ __launch_bounds__(256) void k_gemm_out_mfma(
    const __hip_bfloat16* __restrict__ A, const __hip_bfloat16* __restrict__ B,
    const float* __restrict__ bias, float* __restrict__ C) {
  __shared__ __hip_bfloat16 As[128][32];
  __shared__ __hip_bfloat16 Bs[128][32];
  int t = threadIdx.x;
  int wid = t >> 6, lane = t & 63;
  int m0 = blockIdx.y * 128, n0 = blockIdx.x * 128;
  int wr = wid >> 1, wc = wid & 1;
  f32x4 acc[4][4] = {};
  for (int k0 = 0; k0 < NH; k0 += 32) {
    __syncthreads();
#pragma unroll
    for (int is = 0; is < 2; ++is) {
      int off = is * 4096 + wid * 1024 + lane * 16;
      int r = off >> 6, cb = (off & 63) >> 1;
      gld_lds16(A + (size_t)(m0 + r) * NH + k0 + cb, &As[r][cb]);
      gld_lds16(B + (size_t)(n0 + r) * NH + k0 + cb, &Bs[r][cb]);
    }
    __syncthreads();
    int r16 = lane & 15, kb = (lane >> 4) * 8;
    bf16x8 af[4], bfr[4];
#pragma unroll
    for (int i = 0; i < 4; ++i) {
      af[i]  = *(const bf16x8*)&As[wr * 64 + i * 16 + r16][kb];
      bfr[i] = *(const bf16x8*)&Bs[wc * 64 + i * 16 + r16][kb];
    }
#pragma unroll
    for (int i = 0; i < 4; ++i)
#pragma unroll
      for (int j = 0; j < 4; ++j)
        acc[i][j] = __builtin_amdgcn_mfma_f32_16x16x32_bf16(af[i], bfr[j], acc[i][j], 0, 0, 0);
  }
  int r16 = lane & 15, rg = lane >> 4;
#pragma unroll
  for (int i = 0; i < 4; ++i)
#pragma unroll
    for (int j = 0; j < 4; ++j) {
      int ccol = n0 + wc * 64 + j * 16 + r16;
      if (ccol < NVOUT) {
        float bs = bias[ccol];
#pragma unroll
        for (int q = 0; q < 4; ++q) {
          int crow = m0 + wr * 64 + i * 16 + rg * 4 + q;  // = l*64+b
          int l = crow >> 6, b = crow & 63;
          C[((size_t)b * NL + l) * NVOUT + ccol] = acc[i][j][q] + bs;
        }
      }
    }
}

// ---------------------------------------------------------------------------
// Pre-gather decoder one-hot input term (teacher forcing known upfront).
// ---------------------------------------------------------------------------
__global__ __launch_bounds__(256) void k_pregather(
    const float* __restrict__ Wih, const float* __restrict__ bih,
    const int* __restrict__ gt, float* __restrict__ Gdec) {
  int ib = blockIdx.x;              // i*64+b
  int i = ib >> 6, b = ib & 63;
  int tok = (i > 0) ? gt[b * NL + (i - 1)] : -1;
  for (int g = threadIdx.x; g < G3; g += 256) {
    float v = bih[g];
    if (tok >= 0) v += Wih[g * (NH + NVOUT) + NH + tok];
    Gdec[ib * G3 + g] = v;
  }
}

// ---------------------------------------------------------------------------
// Encoder scan: 32 WGs x 768 thr, 2 batches per WG.
// Gi rows are in X order: row = b*64+s.
// ---------------------------------------------------------------------------
__global__ __launch_bounds__(768) void k_encoder(
    const float* __restrict__ Gi, const float* __restrict__ WhhT,
    const float* __restrict__ bhh, float* __restrict__ enc_h) {
  __shared__ float hbuf[2][NH];
  __shared__ float ghbuf[2][G3];
  int t = threadIdx.x;
  int b0 = blockIdx.x * 2;
  if (t < 512) hbuf[t >> 8][t & 255] = 0.f;
  __syncthreads();
  for (int s = 0; s < NS; ++s) {
    {
      int g = t;
      float a0 = 0.f, a1 = 0.f;
#pragma unroll 8
      for (int k = 0; k < NH; ++k) {
        float w = WhhT[k * G3 + g];
        a0 = fmaf(hbuf[0][k], w, a0);
        a1 = fmaf(hbuf[1][k], w, a1);
      }
      float bb = bhh[g];
      ghbuf[0][g] = a0 + bb;
      ghbuf[1][g] = a1 + bb;
    }
    __syncthreads();
    if (t < 512) {
      int bl = t >> 8, j = t & 255, b = b0 + bl;
      const float* gi = Gi + ((size_t)b * 64 + s) * G3;   // X-order rows
      float r = 1.f / (1.f + __expf(-(gi[j] + ghbuf[bl][j])));
      float z = 1.f / (1.f + __expf(-(gi[256 + j] + ghbuf[bl][256 + j])));
      float n = tanhf(gi[512 + j] + r * ghbuf[bl][512 + j]);
      float hn = (1.f - z) * n + z * hbuf[bl][j];
      hbuf[bl][j] = hn;
      enc_h[(s * 64 + b) * NH + j] = hn;
    }
    __syncthreads();
  }
}

// enc_score[s][b] = enc_h[s][b] . w_enc
__global__ __launch_bounds__(256) void k_enc_score(
    const float* __restrict__ enc_h, const float* __restrict__ att_w,
    float* __restrict__ score) {
  int row = blockIdx.x * 4 + (threadIdx.x >> 6);
  int lane = threadIdx.x & 63;
  const float* hrow = enc_h + row * NH;
  const float* we = att_w + NH;
  float p = 0.f;
#pragma unroll
  for (int j = lane; j < NH; j += 64) p += hrow[j] * we[j];
#pragma unroll
  for (int off = 32; off; off >>= 1) p += __shfl_xor(p, off, 64);
  if (lane == 0) score[row] = p;
}

// ---------------------------------------------------------------------------
// Decoder scan: 32 WGs x 768 thr, 2 batches per WG. Emits dec_h in bf16.
// ---------------------------------------------------------------------------
__global__ __launch_bounds__(768) void k_decoder(
    const float* __restrict__ Gdec, const float* __restrict__ WihT,
    const float* __restrict__ WhhT, const float* __restrict__ bhh,
    const float* __restrict__ enc_h, const float* __restrict__ escore,
    const float* __restrict__ att_w, const float* __restrict__ att_b,
    __hip_bfloat16* __restrict__ dec_hb) {
  __shared__ float hbuf[2][NH];
  __shared__ float ctx[2][NH];
  __shared__ float gibuf[2][G3];
  __shared__ float ghbuf[2][G3];
  __shared__ float wts[2][NS];
  __shared__ float sc[2];
  int t = threadIdx.x;
  int b0 = blockIdx.x * 2;
  if (t < 512) {
    int bl = t >> 8, j = t & 255;
    hbuf[bl][j] = enc_h[((NS - 1) * 64 + b0 + bl) * NH + j];
  }
  __syncthreads();
  float attb = att_b[0];
  for (int i = 0; i < NL; ++i) {
    if (t < 128) {
      int bl = t >> 6, lane = t & 63;
      float p = 0.f;
#pragma unroll
      for (int j = lane; j < NH; j += 64) p += hbuf[bl][j] * att_w[j];
#pragma unroll
      for (int off = 32; off; off >>= 1) p += __shfl_xor(p, off, 64);
      if (lane == 0) sc[bl] = p;
    }
    __syncthreads();
    if (t < 128) {
      int bl = t >> 6, s_ = t & 63, b = b0 + bl;
      float lg = fmaxf(escore[s_ * 64 + b] + sc[bl] + attb, 0.f);
      float mx = lg;
#pragma unroll
      for (int off = 32; off; off >>= 1) mx = fmaxf(mx, __shfl_xor(mx, off, 64));
      float e = __expf(lg - mx);
      float sm = e;
#pragma unroll
      for (int off = 32; off; off >>= 1) sm += __shfl_xor(sm, off, 64);
      wts[bl][s_] = e / sm;
    }
    __syncthreads();
    if (t < 512) {
      int bl = t >> 8, j = t & 255, b = b0 + bl;
      float c = 0.f;
#pragma unroll 4
      for (int s_ = 0; s_ < NS; ++s_) c += wts[bl][s_] * enc_h[(s_ * 64 + b) * NH + j];
      ctx[bl][j] = c;
    }
    __syncthreads();
    {
      int g = t;
      float gi0 = 0.f, gi1 = 0.f, gh0 = 0.f, gh1 = 0.f;
#pragma unroll 4
      for (int k = 0; k < NH; ++k) {
        float wi = WihT[k * G3 + g];
        float wh = WhhT[k * G3 + g];
        gi0 = fmaf(ctx[0][k], wi, gi0);
        gi1 = fmaf(ctx[1][k], wi, gi1);
        gh0 = fmaf(hbuf[0][k], wh, gh0);
        gh1 = fmaf(hbuf[1][k], wh, gh1);
      }
      float bb = bhh[g];
      gibuf[0][g] = gi0 + Gdec[(i * 64 + b0) * G3 + g];
      gibuf[1][g] = gi1 + Gdec[(i * 64 + b0 + 1) * G3 + g];
      ghbuf[0][g] = gh0 + bb;
      ghbuf[1][g] = gh1 + bb;
    }
    __syncthreads();
    if (t < 512) {
      int bl = t >> 8, j = t & 255, b = b0 + bl;
      float r = 1.f / (1.f + __expf(-(gibuf[bl][j] + ghbuf[bl][j])));
      float z = 1.f / (1.f + __expf(-(gibuf[bl][256 + j] + ghbuf[bl][256 + j])));
      float n = tanhf(gibuf[bl][512 + j] + r * ghbuf[bl][512 + j]);
      float hn = (1.f - z) * n + z * hbuf[bl][j];
      hbuf[bl][j] = hn;
      dec_hb[(i * 64 + b) * NH + j] = __float2bfloat16(hn);
    }
    __syncthreads();
  }
}

// In-place row log-softmax over VOUT (one WG per (b,l) row).
__global__ __launch_bounds__(256) void k_logsoftmax(float* __restrict__ out) {
  float* x = out + (size_t)blockIdx.x * NVOUT;
  __shared__ float red[256];
  int t = threadIdx.x;
  float mx = -1e30f;
  for (int v = t; v < NVOUT; v += 256) mx = fmaxf(mx, x[v]);
  red[t] = mx; __syncthreads();
  for (int off = 128; off; off >>= 1) {
    if (t < off) red[t] = fmaxf(red[t], red[t + off]);
    __syncthreads();
  }
  mx = red[0]; __syncthreads();
  float sm = 0.f;
  for (int v = t; v < NVOUT; v += 256) sm += __expf(x[v] - mx);
  red[t] = sm; __syncthreads();
  for (int off = 128; off; off >>= 1) {
    if (t < off) red[t] += red[t + off];
    __syncthreads();
  }
  float lse = mx + logf(red[0]);
  for (int v = t; v < NVOUT; v += 256) x[v] -= lse;
}

// ---------------------------------------------------------------------------
extern "C" void kernel_launch(void* const* d_in, const int* in_sizes, int n_in,
                              void* d_out, int out_size, void* d_ws, size_t ws_size,
                              hipStream_t stream) {
  const float* X        = (const float*)d_in[0];
  const int*   gt       = (const int*)  d_in[1];
  const float* enc_Wih  = (const float*)d_in[2];
  const float* enc_Whh  = (const float*)d_in[3];
  const float* enc_bih  = (const float*)d_in[4];
  const float* enc_bhh  = (const float*)d_in[5];
  const float* att_w    = (const float*)d_in[6];
  const float* att_b    = (const float*)d_in[7];
  const float* dec_Wih  = (const float*)d_in[8];
  const float* dec_Whh  = (const float*)d_in[9];
  const float* dec_bih  = (const float*)d_in[10];
  const float* dec_bhh  = (const float*)d_in[11];
  const float* out_W    = (const float*)d_in[12];
  const float* out_b    = (const float*)d_in[13];
  float* out = (float*)d_out;

  // workspace carve-up (~136 MB total)
  float* p = (float*)d_ws;
  float* WhhTe = p; p += NH * G3;
  float* WhhTd = p; p += NH * G3;
  float* WihTd = p; p += NH * G3;
  float* Gienc = p; p += NS * NB * G3;       // rows in X order (b*64+s)
  float* Gdec  = p; p += NL * NB * G3;
  float* ench  = p; p += NS * NB * NH;
  float* escore = p; p += NS * NB;
  __hip_bfloat16* q = (__hip_bfloat16*)p;
  __hip_bfloat16* Xb    = q; q += (size_t)4096 * KP1;     // [4096][10016]
  __hip_bfloat16* Wencb = q; q += (size_t)G3 * KP1;       // [768][10016]
  __hip_bfloat16* Woutb = q; q += (size_t)NOUTP * NH;     // [10112][256]
  __hip_bfloat16* dechb = q; q += (size_t)NL * NB * NH;   // [4096][256]

  // conversions + transposes + pregather (all independent)
  k_cvt_pad<<<4096, 256, 0, stream>>>(X, Xb, 4096, NVIN, KP1);
  k_cvt_pad<<<G3, 256, 0, stream>>>(enc_Wih, Wencb, G3, NVIN, KP1);
  k_cvt_pad<<<NOUTP, 256, 0, stream>>>(out_W, Woutb, NVOUT, NH, NH);
  k_transpose<<<768, 256, 0, stream>>>(enc_Whh, WhhTe, G3, NH, NH);
  k_transpose<<<768, 256, 0, stream>>>(dec_Whh, WhhTd, G3, NH, NH);
  k_transpose<<<768, 256, 0, stream>>>(dec_Wih, WihTd, G3, NH, NH + NVOUT);
  k_pregather<<<NL * NB, 256, 0, stream>>>(dec_Wih, dec_bih, gt, Gdec);

  k_gemm_enc_mfma<<<dim3(6, 32), 256, 0, stream>>>(Xb, Wencb, enc_bih, Gienc);
  k_encoder<<<32, 768, 0, stream>>>(Gienc, WhhTe, enc_bhh, ench);
  k_enc_score<<<1024, 256, 0, stream>>>(ench, att_w, escore);
  k_decoder<<<32, 768, 0, stream>>>(Gdec, WihTd, WhhTd, dec_bhh, ench, escore,
                                    att_w, att_b, dechb);
  k_gemm_out_mfma<<<dim3(79, 32), 256, 0, stream>>>(dechb, Woutb, out_b, out);
  k_logsoftmax<<<NB * NL, 256, 0, stream>>>(out);
}

// Round 3
// 1587.505 us; speedup vs baseline: 2.2386x; 1.4387x over previous
//
#include <hip/hip_runtime.h>
#include <hip/hip_bf16.h>
#include <math.h>

// Problem dims (fixed by the reference)
#define NB 64      // batch
#define NS 64      // encoder steps
#define NL 64      // decoder steps
#define NH 256     // hidden
#define G3 768     // 3*NH (gates r,z,n)
#define NVIN 10000
#define NVOUT 10000
#define KP1 10016   // NVIN padded to multiple of 32 (BK) for enc GEMM
#define NOUTP 10112 // NVOUT padded to multiple of 128 (BN) for out GEMM

typedef __attribute__((ext_vector_type(8))) short bf16x8;  // 8 bf16 (4 VGPRs)
typedef __attribute__((ext_vector_type(4))) float f32x4;   // MFMA accumulator

// async global->LDS, 16B per lane (dest must be wave-uniform base + lane*16)
__device__ __forceinline__ void gld_lds16(const __hip_bfloat16* g, __hip_bfloat16* l) {
  __builtin_amdgcn_global_load_lds(
      (const __attribute__((address_space(1))) unsigned int*)(const void*)g,
      (__attribute__((address_space(3))) unsigned int*)(void*)l, 16, 0, 0);
}

__device__ __forceinline__ unsigned int f2bf(float f) {  // RNE fp32->bf16 bits
  unsigned int u = __float_as_uint(f);
  return (u + 0x7fff + ((u >> 16) & 1)) >> 16;
}

// ---------------------------------------------------------------------------
// fp32 -> bf16 row-wise convert with row/col zero-padding.
// ---------------------------------------------------------------------------
__global__ __launch_bounds__(256) void k_cvt_pad(
    const float* __restrict__ in, __hip_bfloat16* __restrict__ out,
    int in_rows, int in_cols, int out_cols) {
  int r = blockIdx.x;
  const float* src = in + (size_t)r * in_cols;
  __hip_bfloat16* dst = out + (size_t)r * out_cols;
  bool live = r < in_rows;
  for (int c = threadIdx.x * 4; c < out_cols; c += 1024) {
    __hip_bfloat16 v[4];
    if (live && c < in_cols) {
      float4 f = *(const float4*)(src + c);
      v[0] = __float2bfloat16(f.x); v[1] = __float2bfloat16(f.y);
      v[2] = __float2bfloat16(f.z); v[3] = __float2bfloat16(f.w);
    } else {
      v[0] = v[1] = v[2] = v[3] = __float2bfloat16(0.f);
    }
    *(ushort4*)(dst + c) = *(const ushort4*)v;
  }
}

// ---------------------------------------------------------------------------
// Transpose-pack recurrent weights: in fp32 [G3][stride] (row g, col k),
// out u32 [NH/2][G3]: out[k2*G3+g] = bf16(in[g][2k2]) | bf16(in[g][2k2+1])<<16
// ---------------------------------------------------------------------------
__global__ __launch_bounds__(256) void k_tpack(
    const float* __restrict__ in, int stride, unsigned int* __restrict__ out) {
  int idx = blockIdx.x * 256 + threadIdx.x;        // 128*768 total
  int k2 = idx / G3, g = idx % G3;
  float lo = in[(size_t)g * stride + 2 * k2];
  float hi = in[(size_t)g * stride + 2 * k2 + 1];
  out[idx] = f2bf(lo) | (f2bf(hi) << 16);
}

// ---------------------------------------------------------------------------
// MFMA GEMM (NT): C[m][n] = sum_k A[m][k]*B[n][k] + bias[n]
// A [4096][KP1] bf16 (row = b*64+s, X order), B [768][KP1] bf16.
// ---------------------------------------------------------------------------
__global__ __launch_bounds__(256) void k_gemm_enc_mfma(
    const __hip_bfloat16* __restrict__ A, const __hip_bfloat16* __restrict__ B,
    const float* __restrict__ bias, float* __restrict__ C) {
  __shared__ __hip_bfloat16 As[128][32];
  __shared__ __hip_bfloat16 Bs[128][32];
  int t = threadIdx.x;
  int wid = t >> 6, lane = t & 63;
  int m0 = blockIdx.y * 128, n0 = blockIdx.x * 128;
  int wr = wid >> 1, wc = wid & 1;
  f32x4 acc[4][4] = {};
  for (int k0 = 0; k0 < KP1; k0 += 32) {
    __syncthreads();
#pragma unroll
    for (int is = 0; is < 2; ++is) {
      int off = is * 4096 + wid * 1024 + lane * 16;
      int r = off >> 6, cb = (off & 63) >> 1;
      gld_lds16(A + (size_t)(m0 + r) * KP1 + k0 + cb, &As[r][cb]);
      gld_lds16(B + (size_t)(n0 + r) * KP1 + k0 + cb, &Bs[r][cb]);
    }
    __syncthreads();
    int r16 = lane & 15, kb = (lane >> 4) * 8;
    bf16x8 af[4], bfr[4];
#pragma unroll
    for (int i = 0; i < 4; ++i) {
      af[i]  = *(const bf16x8*)&As[wr * 64 + i * 16 + r16][kb];
      bfr[i] = *(const bf16x8*)&Bs[wc * 64 + i * 16 + r16][kb];
    }
#pragma unroll
    for (int i = 0; i < 4; ++i)
#pragma unroll
      for (int j = 0; j < 4; ++j)
        acc[i][j] = __builtin_amdgcn_mfma_f32_16x16x32_bf16(af[i], bfr[j], acc[i][j], 0, 0, 0);
  }
  int r16 = lane & 15, rg = lane >> 4;
#pragma unroll
  for (int i = 0; i < 4; ++i)
#pragma unroll
    for (int j = 0; j < 4; ++j) {
      int ccol = n0 + wc * 64 + j * 16 + r16;
      float bs = bias[ccol];
#pragma unroll
      for (int q = 0; q < 4; ++q) {
        int crow = m0 + wr * 64 + i * 16 + rg * 4 + q;
        C[(size_t)crow * G3 + ccol] = acc[i][j][q] + bs;
      }
    }
}

// ---------------------------------------------------------------------------
// MFMA GEMM out: A dec_h bf16 [4096][256] (row = l*64+b), B out_W bf16
// [10112][256] zero-padded. C row (b*NL+l), col guard < NVOUT.
// ---------------------------------------------------------------------------
__global__ __launch_bounds__(256) void k_gemm_out_mfma(
    const __hip_bfloat16* __restrict__ A, const __hip_bfloat16* __restrict__ B,
    const float* __restrict__ bias, float* __restrict__ C) {
  __shared__ __hip_bfloat16 As[128][32];
  __shared__ __hip_bfloat16 Bs[128][32];
  int t = threadIdx.x;
  int wid = t >> 6, lane = t & 63;
  int m0 = blockIdx.y * 128, n0 = blockIdx.x * 128;
  int wr = wid >> 1, wc = wid & 1;
  f32x4 acc[4][4] = {};
  for (int k0 = 0; k0 < NH; k0 += 32) {
    __syncthreads();
#pragma unroll
    for (int is = 0; is < 2; ++is) {
      int off = is * 4096 + wid * 1024 + lane * 16;
      int r = off >> 6, cb = (off & 63) >> 1;
      gld_lds16(A + (size_t)(m0 + r) * NH + k0 + cb, &As[r][cb]);
      gld_lds16(B + (size_t)(n0 + r) * NH + k0 + cb, &Bs[r][cb]);
    }
    __syncthreads();
    int r16 = lane & 15, kb = (lane >> 4) * 8;
    bf16x8 af[4], bfr[4];
#pragma unroll
    for (int i = 0; i < 4; ++i) {
      af[i]  = *(const bf16x8*)&As[wr * 64 + i * 16 + r16][kb];
      bfr[i] = *(const bf16x8*)&Bs[wc * 64 + i * 16 + r16][kb];
    }
#pragma unroll
    for (int i = 0; i < 4; ++i)
#pragma unroll
      for (int j = 0; j < 4; ++j)
        acc[i][j] = __builtin_amdgcn_mfma_f32_16x16x32_bf16(af[i], bfr[j], acc[i][j], 0, 0, 0);
  }
  int r16 = lane & 15, rg = lane >> 4;
#pragma unroll
  for (int i = 0; i < 4; ++i)
#pragma unroll
    for (int j = 0; j < 4; ++j) {
      int ccol = n0 + wc * 64 + j * 16 + r16;
      if (ccol < NVOUT) {
        float bs = bias[ccol];
#pragma unroll
        for (int q = 0; q < 4; ++q) {
          int crow = m0 + wr * 64 + i * 16 + rg * 4 + q;  // = l*64+b
          int l = crow >> 6, b = crow & 63;
          C[((size_t)b * NL + l) * NVOUT + ccol] = acc[i][j][q] + bs;
        }
      }
    }
}

// ---------------------------------------------------------------------------
// Pre-gather decoder one-hot input term.
// ---------------------------------------------------------------------------
__global__ __launch_bounds__(256) void k_pregather(
    const float* __restrict__ Wih, const float* __restrict__ bih,
    const int* __restrict__ gt, float* __restrict__ Gdec) {
  int ib = blockIdx.x;              // i*64+b
  int i = ib >> 6, b = ib & 63;
  int tok = (i > 0) ? gt[b * NL + (i - 1)] : -1;
  for (int g = threadIdx.x; g < G3; g += 256) {
    float v = bih[g];
    if (tok >= 0) v += Wih[g * (NH + NVOUT) + NH + tok];
    Gdec[ib * G3 + g] = v;
  }
}

// ---------------------------------------------------------------------------
// Encoder scan: 64 WGs x 1024 thr, ONE batch per WG (b = blockIdx.x).
// Per step, phase D: 3072 jobs (gate g x k-quarter q), 32 packed-bf16 loads
// + 64 FMA each -> part[q][g]; phase E: 256 thr reduce + gates + h update.
// Gi rows are in X order: row = b*64+s.
// ---------------------------------------------------------------------------
__global__ __launch_bounds__(1024) void k_encoder(
    const float* __restrict__ Gi, const unsigned int* __restrict__ Whp,
    const float* __restrict__ bhh, float* __restrict__ enc_h) {
  __shared__ float hbuf[NH];
  __shared__ float part[4][G3];
  int t = threadIdx.x;
  int b = blockIdx.x;
  if (t < NH) hbuf[t] = 0.f;
  __syncthreads();
  for (int s = 0; s < NS; ++s) {
    // D: partial GEMV
#pragma unroll
    for (int i = 0; i < 3; ++i) {
      int idx = i * 1024 + t;              // [0,3072)
      int q = idx / G3, g = idx - q * G3;  // k-quarter, gate
      int k2b = q * 32;                    // 32 k-pairs = 64 k
      float acc = 0.f;
#pragma unroll 8
      for (int k2 = 0; k2 < 32; ++k2) {
        unsigned int u = Whp[(k2b + k2) * G3 + g];
        float wlo = __uint_as_float(u << 16);
        float whi = __uint_as_float(u & 0xffff0000u);
        acc = fmaf(hbuf[2 * (k2b + k2)], wlo, acc);
        acc = fmaf(hbuf[2 * (k2b + k2) + 1], whi, acc);
      }
      part[q][g] = acc;
    }
    __syncthreads();
    // E: reduce + gates + update
    if (t < NH) {
      int j = t;
      const float* gi = Gi + ((size_t)b * 64 + s) * G3;
      float ghr = part[0][j] + part[1][j] + part[2][j] + part[3][j] + bhh[j];
      float ghz = part[0][NH + j] + part[1][NH + j] + part[2][NH + j] + part[3][NH + j] + bhh[NH + j];
      float ghn = part[0][2 * NH + j] + part[1][2 * NH + j] + part[2][2 * NH + j] + part[3][2 * NH + j] + bhh[2 * NH + j];
      float r = 1.f / (1.f + __expf(-(gi[j] + ghr)));
      float z = 1.f / (1.f + __expf(-(gi[NH + j] + ghz)));
      float n = tanhf(gi[2 * NH + j] + r * ghn);
      float hn = (1.f - z) * n + z * hbuf[j];
      hbuf[j] = hn;
      enc_h[((size_t)s * 64 + b) * NH + j] = hn;
    }
    __syncthreads();
  }
}

// enc_score[s][b] = enc_h[s][b] . w_enc
__global__ __launch_bounds__(256) void k_enc_score(
    const float* __restrict__ enc_h, const float* __restrict__ att_w,
    float* __restrict__ score) {
  int row = blockIdx.x * 4 + (threadIdx.x >> 6);
  int lane = threadIdx.x & 63;
  const float* hrow = enc_h + row * NH;
  const float* we = att_w + NH;
  float p = 0.f;
#pragma unroll
  for (int j = lane; j < NH; j += 64) p += hrow[j] * we[j];
#pragma unroll
  for (int off = 32; off; off >>= 1) p += __shfl_xor(p, off, 64);
  if (lane == 0) score[row] = p;
}

// ---------------------------------------------------------------------------
// Decoder scan: 64 WGs x 1024 thr, ONE batch per WG.
// Phases per step: AB (wave0: sc dot + softmax) | C partial ctx | CR reduce |
// D partial GEMV (gi & gh, packed bf16 weights) | E gates + h update.
// ---------------------------------------------------------------------------
__global__ __launch_bounds__(1024) void k_decoder(
    const float* __restrict__ Gdec, const unsigned int* __restrict__ Wip,
    const unsigned int* __restrict__ Whp, const float* __restrict__ bhh,
    const float* __restrict__ enc_h, const float* __restrict__ escore,
    const float* __restrict__ att_w, const float* __restrict__ att_b,
    __hip_bfloat16* __restrict__ dec_hb) {
  __shared__ float hbuf[NH];
  __shared__ float ctx[NH];
  __shared__ float wts[NS];
  __shared__ float partc[4][NH];
  __shared__ float part[4][G3];
  int t = threadIdx.x;
  int b = blockIdx.x;
  if (t < NH) hbuf[t] = enc_h[((size_t)(NS - 1) * 64 + b) * NH + t];
  __syncthreads();
  float attb = att_b[0];
  for (int i = 0; i < NL; ++i) {
    // AB: wave 0 computes sc = h . w_dec, then softmax over S
    if (t < 64) {
      float p = 0.f;
#pragma unroll
      for (int q = 0; q < 4; ++q) p += hbuf[t + q * 64] * att_w[t + q * 64];
#pragma unroll
      for (int off = 32; off; off >>= 1) p += __shfl_xor(p, off, 64);
      float lg = fmaxf(escore[t * 64 + b] + p + attb, 0.f);
      float mx = lg;
#pragma unroll
      for (int off = 32; off; off >>= 1) mx = fmaxf(mx, __shfl_xor(mx, off, 64));
      float e = __expf(lg - mx);
      float sm = e;
#pragma unroll
      for (int off = 32; off; off >>= 1) sm += __shfl_xor(sm, off, 64);
      wts[t] = e / sm;
    }
    __syncthreads();
    // C: ctx partials over s-chunks of 16
    {
      int j = t & 255, sq = t >> 8;
      float c = 0.f;
#pragma unroll
      for (int s2 = 0; s2 < 16; ++s2) {
        int s_ = sq * 16 + s2;
        c = fmaf(wts[s_], enc_h[((size_t)s_ * 64 + b) * NH + j], c);
      }
      partc[sq][j] = c;
    }
    __syncthreads();
    // CR: reduce ctx
    if (t < NH) ctx[t] = partc[0][t] + partc[1][t] + partc[2][t] + partc[3][t];
    __syncthreads();
    // D: partial GEMV for gi (ctx @ WihT) and gh (h @ WhhT)
#pragma unroll
    for (int ii = 0; ii < 3; ++ii) {
      int idx = ii * 1024 + t;             // [0,3072)
      int mh = idx / G3, g = idx - mh * G3;  // mh: 0,1=gi halves; 2,3=gh halves
      int k2b = (mh & 1) * 64;             // 64 k-pairs = 128 k per half
      float acc = 0.f;
      if (mh < 2) {
#pragma unroll 8
        for (int k2 = 0; k2 < 64; ++k2) {
          unsigned int u = Wip[(k2b + k2) * G3 + g];
          acc = fmaf(ctx[2 * (k2b + k2)], __uint_as_float(u << 16), acc);
          acc = fmaf(ctx[2 * (k2b + k2) + 1], __uint_as_float(u & 0xffff0000u), acc);
        }
      } else {
#pragma unroll 8
        for (int k2 = 0; k2 < 64; ++k2) {
          unsigned int u = Whp[(k2b + k2) * G3 + g];
          acc = fmaf(hbuf[2 * (k2b + k2)], __uint_as_float(u << 16), acc);
          acc = fmaf(hbuf[2 * (k2b + k2) + 1], __uint_as_float(u & 0xffff0000u), acc);
        }
      }
      part[mh][g] = acc;
    }
    __syncthreads();
    // E: reduce + gates + h update
    if (t < NH) {
      int j = t;
      const float* gd = Gdec + ((size_t)i * 64 + b) * G3;
      float gir = part[0][j] + part[1][j] + gd[j];
      float giz = part[0][NH + j] + part[1][NH + j] + gd[NH + j];
      float gin = part[0][2 * NH + j] + part[1][2 * NH + j] + gd[2 * NH + j];
      float ghr = part[2][j] + part[3][j] + bhh[j];
      float ghz = part[2][NH + j] + part[3][NH + j] + bhh[NH + j];
      float ghn = part[2][2 * NH + j] + part[3][2 * NH + j] + bhh[2 * NH + j];
      float r = 1.f / (1.f + __expf(-(gir + ghr)));
      float z = 1.f / (1.f + __expf(-(giz + ghz)));
      float n = tanhf(gin + r * ghn);
      float hn = (1.f - z) * n + z * hbuf[j];
      hbuf[j] = hn;
      dec_hb[((size_t)i * 64 + b) * NH + j] = __float2bfloat16(hn);
    }
    __syncthreads();
  }
}

// In-place row log-softmax over VOUT (one WG per (b,l) row).
__global__ __launch_bounds__(256) void k_logsoftmax(float* __restrict__ out) {
  float* x = out + (size_t)blockIdx.x * NVOUT;
  __shared__ float red[256];
  int t = threadIdx.x;
  float mx = -1e30f;
  for (int v = t; v < NVOUT; v += 256) mx = fmaxf(mx, x[v]);
  red[t] = mx; __syncthreads();
  for (int off = 128; off; off >>= 1) {
    if (t < off) red[t] = fmaxf(red[t], red[t + off]);
    __syncthreads();
  }
  mx = red[0]; __syncthreads();
  float sm = 0.f;
  for (int v = t; v < NVOUT; v += 256) sm += __expf(x[v] - mx);
  red[t] = sm; __syncthreads();
  for (int off = 128; off; off >>= 1) {
    if (t < off) red[t] += red[t + off];
    __syncthreads();
  }
  float lse = mx + logf(red[0]);
  for (int v = t; v < NVOUT; v += 256) x[v] -= lse;
}

// ---------------------------------------------------------------------------
extern "C" void kernel_launch(void* const* d_in, const int* in_sizes, int n_in,
                              void* d_out, int out_size, void* d_ws, size_t ws_size,
                              hipStream_t stream) {
  const float* X        = (const float*)d_in[0];
  const int*   gt       = (const int*)  d_in[1];
  const float* enc_Wih  = (const float*)d_in[2];
  const float* enc_Whh  = (const float*)d_in[3];
  const float* enc_bih  = (const float*)d_in[4];
  const float* enc_bhh  = (const float*)d_in[5];
  const float* att_w    = (const float*)d_in[6];
  const float* att_b    = (const float*)d_in[7];
  const float* dec_Wih  = (const float*)d_in[8];
  const float* dec_Whh  = (const float*)d_in[9];
  const float* dec_bih  = (const float*)d_in[10];
  const float* dec_bhh  = (const float*)d_in[11];
  const float* out_W    = (const float*)d_in[12];
  const float* out_b    = (const float*)d_in[13];
  float* out = (float*)d_out;

  // workspace carve-up
  float* p = (float*)d_ws;
  unsigned int* Whp_e = (unsigned int*)p; p += (NH / 2) * G3;   // packed enc_Whh
  unsigned int* Whp_d = (unsigned int*)p; p += (NH / 2) * G3;   // packed dec_Whh
  unsigned int* Wip_d = (unsigned int*)p; p += (NH / 2) * G3;   // packed dec_Wih[:, :NH]
  float* Gienc = p; p += NS * NB * G3;       // rows in X order (b*64+s)
  float* Gdec  = p; p += NL * NB * G3;
  float* ench  = p; p += NS * NB * NH;
  float* escore = p; p += NS * NB;
  __hip_bfloat16* q = (__hip_bfloat16*)p;
  __hip_bfloat16* Xb    = q; q += (size_t)4096 * KP1;     // [4096][10016]
  __hip_bfloat16* Wencb = q; q += (size_t)G3 * KP1;       // [768][10016]
  __hip_bfloat16* Woutb = q; q += (size_t)NOUTP * NH;     // [10112][256]
  __hip_bfloat16* dechb = q; q += (size_t)NL * NB * NH;   // [4096][256]

  // prep (all independent)
  k_cvt_pad<<<4096, 256, 0, stream>>>(X, Xb, 4096, NVIN, KP1);
  k_cvt_pad<<<G3, 256, 0, stream>>>(enc_Wih, Wencb, G3, NVIN, KP1);
  k_cvt_pad<<<NOUTP, 256, 0, stream>>>(out_W, Woutb, NVOUT, NH, NH);
  k_tpack<<<384, 256, 0, stream>>>(enc_Whh, NH, Whp_e);
  k_tpack<<<384, 256, 0, stream>>>(dec_Whh, NH, Whp_d);
  k_tpack<<<384, 256, 0, stream>>>(dec_Wih, NH + NVOUT, Wip_d);
  k_pregather<<<NL * NB, 256, 0, stream>>>(dec_Wih, dec_bih, gt, Gdec);

  k_gemm_enc_mfma<<<dim3(6, 32), 256, 0, stream>>>(Xb, Wencb, enc_bih, Gienc);
  k_encoder<<<64, 1024, 0, stream>>>(Gienc, Whp_e, enc_bhh, ench);
  k_enc_score<<<1024, 256, 0, stream>>>(ench, att_w, escore);
  k_decoder<<<64, 1024, 0, stream>>>(Gdec, Wip_d, Whp_d, dec_bhh, ench, escore,
                                     att_w, att_b, dechb);
  k_gemm_out_mfma<<<dim3(79, 32), 256, 0, stream>>>(dechb, Woutb, out_b, out);
  k_logsoftmax<<<NB * NL, 256, 0, stream>>>(out);
}